// Round 4
// baseline (5109.968 us; speedup 1.0000x reference)
//
#include <hip/hip_runtime.h>
#include <cstddef>
#include <cstdint>

#define LANG 50257
#define EDIM 512
#define HDIM 1024
#define ADIM 512
#define SLEN 1024
#define NSTEP 25
#define TEMPF 10.0f
#define SOSIDX 1
#define VOFF (NSTEP * LANG)
#define NBLK 256
#define NTHR 1024
#define NGRP 16
#define GSZ  (NBLK / NGRP)

// ---- ws byte offsets --------------------------------------------------------
#define OFF_OUTWB  0u                    // bf16 out_W  50257*1536*2
#define OFF_EMBTB  154389504u            // bf16 emb_T  50257*512*2
#define OFF_P      205852672u            // fp32 P[s][a] 1024*512
#define OFF_EMBT   207949824u            // fp32 embT[a][s] 512*1024
#define OFF_ESC    210046976u            // 1024
#define OFF_H      210051072u            // 2*1024
#define OFF_HPROJ8 210059264u            // 8*512
#define OFF_EANX8  210075648u            // 8*512
#define OFF_DENWP  210092032u            // 256
#define OFF_SDENP  210093056u            // 256
#define OFF_ATTN   210094080u            // 512
#define OFF_BAR    210096128u            // counters (memset each launch)

typedef __attribute__((ext_vector_type(4))) float f4v;

__device__ __forceinline__ float wred(float x) {
#pragma unroll
  for (int off = 32; off; off >>= 1) x += __shfl_down(x, off);
  return x;
}

__device__ __forceinline__ unsigned short f2bf(float x) {
  unsigned u = __float_as_uint(x);
  u = u + 0x7FFFu + ((u >> 16) & 1u);   // RNE
  return (unsigned short)(u >> 16);
}

// tree barrier: 16 group counters + root + gen. Monotonic; reset by memset.
__device__ __forceinline__ void gridbar(unsigned* bar, int bid, unsigned round) {
  __syncthreads();
  if (threadIdx.x == 0) {
    __threadfence();
    int g = bid & (NGRP - 1);
    unsigned t = __hip_atomic_fetch_add(&bar[g * 16], 1u, __ATOMIC_RELAXED, __HIP_MEMORY_SCOPE_AGENT);
    if ((t % GSZ) == GSZ - 1) {
      unsigned r = __hip_atomic_fetch_add(&bar[NGRP * 16], 1u, __ATOMIC_RELAXED, __HIP_MEMORY_SCOPE_AGENT);
      if ((r % NGRP) == NGRP - 1) {
        __threadfence();
        __hip_atomic_store(&bar[NGRP * 16 + 16], round, __ATOMIC_RELEASE, __HIP_MEMORY_SCOPE_AGENT);
      }
    }
    while (__hip_atomic_load(&bar[NGRP * 16 + 16], __ATOMIC_ACQUIRE, __HIP_MEMORY_SCOPE_AGENT) < round)
      __builtin_amdgcn_s_sleep(1);
    __threadfence();
  }
  __syncthreads();
}

__global__ __launch_bounds__(NTHR) void k_decoder(
    const float* __restrict__ hidden, const float* __restrict__ emb_src,
    const float* __restrict__ emb_T,  const float* __restrict__ W_ih,
    const float* __restrict__ W_hh,   const float* __restrict__ b_ih,
    const float* __restrict__ b_hh,   const float* __restrict__ W1,
    const float* __restrict__ b1,     const float* __restrict__ vvec,
    const float* __restrict__ out_W,  const float* __restrict__ out_b,
    float* __restrict__ out, char* __restrict__ wsb) {
  __shared__ __align__(16) float smem[9776];
  const int tid = threadIdx.x, bid = blockIdx.x;
  const int wid = tid >> 6, lane = tid & 63;

  float* P      = (float*)(wsb + OFF_P);
  float* embT   = (float*)(wsb + OFF_EMBT);
  float* esc    = (float*)(wsb + OFF_ESC);
  float* hws    = (float*)(wsb + OFF_H);
  float* hproj8 = (float*)(wsb + OFF_HPROJ8);
  float* eanx8  = (float*)(wsb + OFF_EANX8);
  float* denwp  = (float*)(wsb + OFF_DENWP);
  float* sdenp  = (float*)(wsb + OFF_SDENP);
  float* attn   = (float*)(wsb + OFF_ATTN);
  unsigned* bar = (unsigned*)(wsb + OFF_BAR);
  const uint4* oW4 = (const uint4*)(wsb + OFF_OUTWB);
  const uint4* eT4 = (const uint4*)(wsb + OFF_EMBTB);
  unsigned rnd = 0;

  // ================= pre-phase: conversions (nt loads), P, embT, inits ======
  {
    uint2* dst = (uint2*)(wsb + OFF_OUTWB);
    const f4v* src = (const f4v*)out_W;
    for (int i = bid * NTHR + tid; i < 19298688; i += NBLK * NTHR) {
      f4v f = __builtin_nontemporal_load(src + i);
      dst[i] = make_uint2((unsigned)f2bf(f.x) | ((unsigned)f2bf(f.y) << 16),
                          (unsigned)f2bf(f.z) | ((unsigned)f2bf(f.w) << 16));
    }
    uint2* dst2 = (uint2*)(wsb + OFF_EMBTB);
    const f4v* src2 = (const f4v*)emb_T;
    for (int i = bid * NTHR + tid; i < 6432896; i += NBLK * NTHR) {
      f4v f = __builtin_nontemporal_load(src2 + i);
      dst2[i] = make_uint2((unsigned)f2bf(f.x) | ((unsigned)f2bf(f.y) << 16),
                           (unsigned)f2bf(f.z) | ((unsigned)f2bf(f.w) << 16));
    }
    // P = emb_src @ W1[:A] + b1  (4 src rows per block)
    for (int i = tid; i < 4 * ADIM; i += NTHR)
      smem[i] = emb_src[(size_t)bid * 4 * ADIM + i];
    __syncthreads();
    if (tid < ADIM) {
      int a = tid;
      float bb = b1[a];
      float a0 = bb, a1 = bb, a2 = bb, a3 = bb;
      for (int k = 0; k < ADIM; ++k) {
        float w = W1[(size_t)k * ADIM + a];
        a0 += smem[k] * w; a1 += smem[512 + k] * w;
        a2 += smem[1024 + k] * w; a3 += smem[1536 + k] * w;
      }
      P[(size_t)(bid * 4 + 0) * ADIM + a] = a0;
      P[(size_t)(bid * 4 + 1) * ADIM + a] = a1;
      P[(size_t)(bid * 4 + 2) * ADIM + a] = a2;
      P[(size_t)(bid * 4 + 3) * ADIM + a] = a3;
    }
    // embT[a][s] = emb_src[s*A + a]
    {
      int i0 = bid * 2048 + tid, i1 = i0 + 1024;
      embT[i0] = emb_src[(size_t)(i0 & 1023) * ADIM + (i0 >> 10)];
      embT[i1] = emb_src[(size_t)(i1 & 1023) * ADIM + (i1 >> 10)];
    }
    if (bid == 0) {
      for (int i = tid; i < 8 * EDIM; i += NTHR)
        eanx8[i] = (i < EDIM) ? emb_T[(size_t)SOSIDX * EDIM + i] : 0.f;
      if (tid < 256) denwp[tid] = (tid == 0) ? 1.0f : 0.0f;
    }
    if (bid == 1) { for (int i = tid; i < 8 * ADIM; i += NTHR) hproj8[i] = 0.f; }
    if (bid == 2) { hws[tid] = hidden[tid]; }
  }
  rnd++; gridbar(bar, bid, rnd);

  for (int t = 0; t < NSTEP; ++t) {
    const int cur = t & 1, nxt = cur ^ 1;
    float* hold = hws + cur * HDIM;
    float* hnew = hws + nxt * HDIM;

    // ==== P1: GRU (+ hproj outer-product scatter) ===========================
    {
      float easum = 0.f;
      if (tid < EDIM) {
#pragma unroll
        for (int k = 0; k < 8; ++k) easum += eanx8[k * EDIM + tid];
      }
      float dp = 0.f;
      if (tid >= 512 && tid < 768) dp = denwp[tid - 512];
      smem[512 + tid] = hold[tid];
      dp = wred(dp);
      if (tid >= 512 && tid < 768 && lane == 0) smem[1632 + (wid - 8)] = dp;
      __syncthreads();
      float inv = 1.0f / (smem[1632] + smem[1633] + smem[1634] + smem[1635]);
      if (tid < EDIM) smem[tid] = easum * inv;
      __syncthreads();

      int jl = wid & 3, part = wid >> 2;
      int j = bid * 4 + jl;
      float ir = 0.f, iz = 0.f, in_ = 0.f;
#pragma unroll
      for (int k = 0; k < 2; ++k) {
        int e = part * 128 + k * 64 + lane;
        float x = smem[e];
        ir  += W_ih[(size_t)j * EDIM + e] * x;
        iz  += W_ih[(size_t)(j + HDIM) * EDIM + e] * x;
        in_ += W_ih[(size_t)(j + 2 * HDIM) * EDIM + e] * x;
      }
      float hr = 0.f, hz = 0.f, hn = 0.f;
#pragma unroll
      for (int k = 0; k < 4; ++k) {
        int e = part * 256 + k * 64 + lane;
        float x = smem[512 + e];
        hr += W_hh[(size_t)j * HDIM + e] * x;
        hz += W_hh[(size_t)(j + HDIM) * HDIM + e] * x;
        hn += W_hh[(size_t)(j + 2 * HDIM) * HDIM + e] * x;
      }
#pragma unroll
      for (int off = 32; off; off >>= 1) {
        ir += __shfl_down(ir, off);  iz += __shfl_down(iz, off);  in_ += __shfl_down(in_, off);
        hr += __shfl_down(hr, off);  hz += __shfl_down(hz, off);  hn += __shfl_down(hn, off);
      }
      if (lane == 0) {
        float* pb = smem + 1536 + (jl * 4 + part) * 6;
        pb[0] = ir; pb[1] = iz; pb[2] = in_; pb[3] = hr; pb[4] = hz; pb[5] = hn;
      }
      __syncthreads();
      if (tid < 4) {
        int jj = bid * 4 + tid;
        float sir = 0.f, siz = 0.f, sin_ = 0.f, shr = 0.f, shz = 0.f, shn = 0.f;
#pragma unroll
        for (int p = 0; p < 4; ++p) {
          float* pb = smem + 1536 + (tid * 4 + p) * 6;
          sir += pb[0]; siz += pb[1]; sin_ += pb[2];
          shr += pb[3]; shz += pb[4]; shn += pb[5];
        }
        float r = 1.f / (1.f + expf(-(sir + b_ih[jj] + shr + b_hh[jj])));
        float z = 1.f / (1.f + expf(-(siz + b_ih[jj + HDIM] + shz + b_hh[jj + HDIM])));
        float n = tanhf(sin_ + b_ih[jj + 2 * HDIM] + r * (shn + b_hh[jj + 2 * HDIM]));
        float hv = (1.f - z) * n + z * smem[512 + jj];
        hnew[jj] = hv;
        smem[1640 + tid] = hv;
      }
      __syncthreads();
      if (tid < ADIM) {
        float s = 0.f;
#pragma unroll
        for (int jl2 = 0; jl2 < 4; ++jl2)
          s += smem[1640 + jl2] * W1[(size_t)(ADIM + bid * 4 + jl2) * ADIM + tid];
        atomicAdd(&hproj8[(bid & 7) * ADIM + tid], s);
      }
    }
    rnd++; gridbar(bar, bid, rnd);

    // ==== P2: scores (reduce hproj8; esc = exp(v.tanh(P+hp)); sdenp) ========
    {
      float hp = 0.f;
      if (tid < ADIM) {
#pragma unroll
        for (int k = 0; k < 8; ++k) hp += hproj8[k * ADIM + tid];
      }
      if (tid >= 512) smem[tid] = vvec[tid - 512];
      if (tid < ADIM) smem[tid] = hp;
      if (bid < 8 && tid < EDIM) eanx8[bid * EDIM + tid] = 0.f;
      __syncthreads();
      int sl = wid & 3, part = wid >> 2;
      int s = bid * 4 + sl;
      float acc = 0.f;
#pragma unroll
      for (int k = 0; k < 2; ++k) {
        int a = part * 128 + k * 64 + lane;
        acc += smem[512 + a] * tanhf(P[(size_t)s * ADIM + a] + smem[a]);
      }
      acc = wred(acc);
      if (lane == 0) smem[1024 + wid] = acc;
      __syncthreads();
      if (tid < 4) {
        float tot = smem[1024 + tid] + smem[1028 + tid] + smem[1032 + tid] + smem[1036 + tid];
        float e = expf(tot);
        esc[bid * 4 + tid] = e;
        smem[1040 + tid] = e;
      }
      __syncthreads();
      if (tid == 0)
        sdenp[bid] = smem[1040] + smem[1041] + smem[1042] + smem[1043];
    }
    rnd++; gridbar(bar, bid, rnd);

    // ==== P3: attn + w output + zero hproj8 =================================
    {
      float sp = 0.f;
      if (tid >= 512 && tid < 768) sp = sdenp[tid - 512];
      sp = wred(sp);
      if (tid >= 512 && tid < 768 && lane == 0) smem[16 + (wid - 8)] = sp;
      int al = wid & 1, part = wid >> 1;
      int a = bid * 2 + al;
      float acc = 0.f;
#pragma unroll
      for (int k = 0; k < 2; ++k) {
        int s = part * 128 + k * 64 + lane;
        acc += embT[(size_t)a * SLEN + s] * esc[s];
      }
      acc = wred(acc);
      if (lane == 0) smem[32 + wid] = acc;
      __syncthreads();
      float sden_t = smem[16] + smem[17] + smem[18] + smem[19];
      if (tid < 2) {
        float s = 0.f;
#pragma unroll
        for (int p = 0; p < 8; ++p) s += smem[32 + tid + p * 2];
        attn[bid * 2 + tid] = s / sden_t;
      }
      if (bid < 4 && tid < 256)
        out[VOFF + (size_t)t * SLEN + bid * 256 + tid] = esc[bid * 256 + tid] / sden_t;
      if (bid < 8 && tid < ADIM) hproj8[bid * ADIM + tid] = 0.f;
    }
    rnd++; gridbar(bar, bid, rnd);

    // ==== P4: logits (unroll-4 MLP) + local-max-sparse feedback =============
    {
      smem[tid] = hnew[tid];
      if (tid < ADIM) smem[HDIM + tid] = attn[tid];
      __syncthreads();
      const float4* sm4 = (const float4*)smem;
      float* vout = out + (size_t)t * LANG;
      const bool fb = (t + 1 < NSTEP);
      float dsum = 0.f;
      float wmax = -3.4e38f;
      float vvs[13];
      int wv = bid * 16 + wid;
#pragma unroll
      for (int r0 = 0; r0 < 13; r0 += 4) {
        uint4 u[4][3];
#pragma unroll
        for (int q = 0; q < 4; ++q) {
          int r = r0 + q;
          int l = wv + r * 4096;
          if (r < 13 && l < LANG) {
            const uint4* rw = oW4 + (size_t)l * 192;
            u[q][0] = rw[lane];
            u[q][1] = rw[64 + lane];
            u[q][2] = rw[128 + lane];
          }
        }
        float acc[4] = {0.f, 0.f, 0.f, 0.f};
#pragma unroll
        for (int k = 0; k < 3; ++k) {
          float4 b0 = sm4[k * 128 + lane * 2];
          float4 b1 = sm4[k * 128 + lane * 2 + 1];
#pragma unroll
          for (int q = 0; q < 4; ++q) {
            int r = r0 + q;
            int l = wv + r * 4096;
            if (r < 13 && l < LANG) {
              uint4 uu = u[q][k];
              acc[q] += __uint_as_float(uu.x << 16) * b0.x + __uint_as_float(uu.x & 0xFFFF0000u) * b0.y;
              acc[q] += __uint_as_float(uu.y << 16) * b0.z + __uint_as_float(uu.y & 0xFFFF0000u) * b0.w;
              acc[q] += __uint_as_float(uu.z << 16) * b1.x + __uint_as_float(uu.z & 0xFFFF0000u) * b1.y;
              acc[q] += __uint_as_float(uu.w << 16) * b1.z + __uint_as_float(uu.w & 0xFFFF0000u) * b1.w;
            }
          }
        }
#pragma unroll
        for (int off = 32; off; off >>= 1) {
          acc[0] += __shfl_down(acc[0], off);
          acc[1] += __shfl_down(acc[1], off);
          acc[2] += __shfl_down(acc[2], off);
          acc[3] += __shfl_down(acc[3], off);
        }
#pragma unroll
        for (int q = 0; q < 4; ++q) {
          int r = r0 + q;
          int l = wv + r * 4096;
          if (r < 13) {
            float vv = -3.4e38f;
            if (l < LANG) {
              float bc = __shfl(acc[q], 0);
              vv = (bc + out_b[l]) * TEMPF;
              if (lane == 0) __builtin_nontemporal_store(vv, &vout[l]);
              wmax = fmaxf(wmax, vv);
              if (fb) dsum += expf(vv);
            }
            vvs[r] = vv;
          }
        }
      }
      if (lane == 0) { smem[9728 + wid] = wmax; smem[9744 + wid] = dsum; }
      __syncthreads();
      if (fb) {
        if (tid == 0) {
          float tot = 0.f;
#pragma unroll
          for (int p = 0; p < 16; ++p) tot += smem[9744 + p];
          denwp[bid] = tot;
        }
        float bmax = smem[9728];
#pragma unroll
        for (int p = 1; p < 16; ++p) bmax = fmaxf(bmax, smem[9728 + p]);
        float thr = bmax - 18.0f;
        float ae[8] = {0.f, 0.f, 0.f, 0.f, 0.f, 0.f, 0.f, 0.f};
#pragma unroll
        for (int r = 0; r < 13; ++r) {
          int l = wv + r * 4096;
          if (l < LANG && vvs[r] >= thr) {
            float ev = expf(vvs[r]);
            uint4 uu = eT4[(size_t)l * 64 + lane];
            ae[0] += ev * __uint_as_float(uu.x << 16);
            ae[1] += ev * __uint_as_float(uu.x & 0xFFFF0000u);
            ae[2] += ev * __uint_as_float(uu.y << 16);
            ae[3] += ev * __uint_as_float(uu.y & 0xFFFF0000u);
            ae[4] += ev * __uint_as_float(uu.z << 16);
            ae[5] += ev * __uint_as_float(uu.z & 0xFFFF0000u);
            ae[6] += ev * __uint_as_float(uu.w << 16);
            ae[7] += ev * __uint_as_float(uu.w & 0xFFFF0000u);
          }
        }
        float* big = smem + 1536;
#pragma unroll
        for (int i = 0; i < 8; ++i) big[wid * 512 + i * 64 + lane] = ae[i];
        __syncthreads();
#pragma unroll
        for (int st = 8; st; st >>= 1) {
          for (int i = tid; i < st * 512; i += NTHR) big[i] += big[i + st * 512];
          __syncthreads();
        }
        if (tid < 512) {
          int dim = ((tid & 63) << 3) | (tid >> 6);
          atomicAdd(&eanx8[(bid & 7) * EDIM + dim], big[tid]);
        }
      }
    }
    rnd++; gridbar(bar, bid, rnd);
  }
}

extern "C" void kernel_launch(void* const* d_in, const int* in_sizes, int n_in,
                              void* d_out, int out_size, void* d_ws, size_t ws_size,
                              hipStream_t stream) {
  const float* hidden  = (const float*)d_in[0];
  const float* emb_src = (const float*)d_in[1];
  const float* emb_T   = (const float*)d_in[2];
  const float* W_ih    = (const float*)d_in[3];
  const float* W_hh    = (const float*)d_in[4];
  const float* b_ih    = (const float*)d_in[5];
  const float* b_hh    = (const float*)d_in[6];
  const float* attn_W1 = (const float*)d_in[7];
  const float* attn_b1 = (const float*)d_in[8];
  const float* attn_v  = (const float*)d_in[9];
  const float* out_W   = (const float*)d_in[10];
  const float* out_b   = (const float*)d_in[11];
  float* out = (float*)d_out;
  char* wsb  = (char*)d_ws;

  hipMemsetAsync(wsb + OFF_BAR, 0, 2048, stream);

  void* args[] = {
    (void*)&hidden, (void*)&emb_src, (void*)&emb_T, (void*)&W_ih, (void*)&W_hh,
    (void*)&b_ih, (void*)&b_hh, (void*)&attn_W1, (void*)&attn_b1, (void*)&attn_v,
    (void*)&out_W, (void*)&out_b, (void*)&out, (void*)&wsb
  };
  hipLaunchCooperativeKernel((void*)k_decoder, dim3(NBLK), dim3(NTHR), args, 0, stream);
}

// Round 5
// 4796.944 us; speedup vs baseline: 1.0653x; 1.0653x over previous
//
#include <hip/hip_runtime.h>
#include <cstddef>
#include <cstdint>

#define LANG 50257
#define EDIM 512
#define HDIM 1024
#define ADIM 512
#define SLEN 1024
#define NSTEP 25
#define TEMPF 10.0f
#define SOSIDX 1
#define VOFF (NSTEP * LANG)
#define NBLK 256
#define NTHR 1024
#define NGRP 16
#define GSZ  (NBLK / NGRP)

// ---- ws byte offsets --------------------------------------------------------
#define OFF_OUTWB  0u                    // bf16 out_W  50257*1536*2
#define OFF_EMBTB  154389504u            // bf16 emb_T  50257*512*2
#define OFF_P      205852672u            // fp32 P[s][a] 1024*512
#define OFF_EMBT   207949824u            // fp32 embT[a][s] 512*1024
#define OFF_ESC    210046976u            // 1024
#define OFF_H      210051072u            // 2*1024
#define OFF_HPROJ8 210059264u            // 8*512
#define OFF_EANX8  210075648u            // 8*512
#define OFF_DENWP  210092032u            // 256
#define OFF_SDENP  210093056u            // 256
#define OFF_ATTN   210094080u            // 512
#define OFF_BAR    210096128u            // counters (memset each launch)

__device__ __forceinline__ float wred(float x) {
#pragma unroll
  for (int off = 32; off; off >>= 1) x += __shfl_down(x, off);
  return x;
}

__device__ __forceinline__ unsigned short f2bf(float x) {
  unsigned u = __float_as_uint(x);
  u = u + 0x7FFFu + ((u >> 16) & 1u);   // RNE
  return (unsigned short)(u >> 16);
}

// tree barrier: 16 group counters + root + gen. Monotonic; reset by memset.
__device__ __forceinline__ void gridbar(unsigned* bar, int bid, unsigned round) {
  __syncthreads();
  if (threadIdx.x == 0) {
    __threadfence();
    int g = bid & (NGRP - 1);
    unsigned t = __hip_atomic_fetch_add(&bar[g * 16], 1u, __ATOMIC_RELAXED, __HIP_MEMORY_SCOPE_AGENT);
    if ((t % GSZ) == GSZ - 1) {
      unsigned r = __hip_atomic_fetch_add(&bar[NGRP * 16], 1u, __ATOMIC_RELAXED, __HIP_MEMORY_SCOPE_AGENT);
      if ((r % NGRP) == NGRP - 1) {
        __threadfence();
        __hip_atomic_store(&bar[NGRP * 16 + 16], round, __ATOMIC_RELEASE, __HIP_MEMORY_SCOPE_AGENT);
      }
    }
    while (__hip_atomic_load(&bar[NGRP * 16 + 16], __ATOMIC_ACQUIRE, __HIP_MEMORY_SCOPE_AGENT) < round)
      __builtin_amdgcn_s_sleep(1);
    __threadfence();
  }
  __syncthreads();
}

// 1024 threads/block, 4 waves/SIMD: allows up to 128 VGPRs at 1 block/CU.
__global__ __launch_bounds__(NTHR, 4) void k_decoder(
    const float* __restrict__ hidden, const float* __restrict__ emb_src,
    const float* __restrict__ emb_T,  const float* __restrict__ W_ih,
    const float* __restrict__ W_hh,   const float* __restrict__ b_ih,
    const float* __restrict__ b_hh,   const float* __restrict__ W1,
    const float* __restrict__ b1,     const float* __restrict__ vvec,
    const float* __restrict__ out_W,  const float* __restrict__ out_b,
    float* __restrict__ out, char* __restrict__ wsb) {
  __shared__ __align__(16) float smem[9776];
  const int tid = threadIdx.x, bid = blockIdx.x;
  const int wid = tid >> 6, lane = tid & 63;

  float* P      = (float*)(wsb + OFF_P);
  float* embT   = (float*)(wsb + OFF_EMBT);
  float* esc    = (float*)(wsb + OFF_ESC);
  float* hws    = (float*)(wsb + OFF_H);
  float* hproj8 = (float*)(wsb + OFF_HPROJ8);
  float* eanx8  = (float*)(wsb + OFF_EANX8);
  float* denwp  = (float*)(wsb + OFF_DENWP);
  float* sdenp  = (float*)(wsb + OFF_SDENP);
  float* attn   = (float*)(wsb + OFF_ATTN);
  unsigned* bar = (unsigned*)(wsb + OFF_BAR);
  const uint4* oW4 = (const uint4*)(wsb + OFF_OUTWB);
  const uint4* eT4 = (const uint4*)(wsb + OFF_EMBTB);
  unsigned rnd = 0;

  // ================= pre-phase: conversions, P, embT, inits =================
  {
    uint2* dst = (uint2*)(wsb + OFF_OUTWB);
    const float4* src = (const float4*)out_W;
    for (int i = bid * NTHR + tid; i < 19298688; i += NBLK * NTHR) {
      float4 f = src[i];
      dst[i] = make_uint2((unsigned)f2bf(f.x) | ((unsigned)f2bf(f.y) << 16),
                          (unsigned)f2bf(f.z) | ((unsigned)f2bf(f.w) << 16));
    }
    uint2* dst2 = (uint2*)(wsb + OFF_EMBTB);
    const float4* src2 = (const float4*)emb_T;
    for (int i = bid * NTHR + tid; i < 6432896; i += NBLK * NTHR) {
      float4 f = src2[i];
      dst2[i] = make_uint2((unsigned)f2bf(f.x) | ((unsigned)f2bf(f.y) << 16),
                           (unsigned)f2bf(f.z) | ((unsigned)f2bf(f.w) << 16));
    }
    // P = emb_src @ W1[:A] + b1  (4 src rows per block)
    for (int i = tid; i < 4 * ADIM; i += NTHR)
      smem[i] = emb_src[(size_t)bid * 4 * ADIM + i];
    __syncthreads();
    if (tid < ADIM) {
      int a = tid;
      float bb = b1[a];
      float a0 = bb, a1 = bb, a2 = bb, a3 = bb;
      for (int k = 0; k < ADIM; ++k) {
        float w = W1[(size_t)k * ADIM + a];
        a0 += smem[k] * w; a1 += smem[512 + k] * w;
        a2 += smem[1024 + k] * w; a3 += smem[1536 + k] * w;
      }
      P[(size_t)(bid * 4 + 0) * ADIM + a] = a0;
      P[(size_t)(bid * 4 + 1) * ADIM + a] = a1;
      P[(size_t)(bid * 4 + 2) * ADIM + a] = a2;
      P[(size_t)(bid * 4 + 3) * ADIM + a] = a3;
    }
    // embT[a][s] = emb_src[s*A + a]
    {
      int i0 = bid * 2048 + tid, i1 = i0 + 1024;
      embT[i0] = emb_src[(size_t)(i0 & 1023) * ADIM + (i0 >> 10)];
      embT[i1] = emb_src[(size_t)(i1 & 1023) * ADIM + (i1 >> 10)];
    }
    if (bid == 0) {
      for (int i = tid; i < 8 * EDIM; i += NTHR)
        eanx8[i] = (i < EDIM) ? emb_T[(size_t)SOSIDX * EDIM + i] : 0.f;
      if (tid < 256) denwp[tid] = (tid == 0) ? 1.0f : 0.0f;
    }
    if (bid == 1) { for (int i = tid; i < 8 * ADIM; i += NTHR) hproj8[i] = 0.f; }
    if (bid == 2) { hws[tid] = hidden[tid]; }
  }
  rnd++; gridbar(bar, bid, rnd);

  for (int t = 0; t < NSTEP; ++t) {
    const int cur = t & 1, nxt = cur ^ 1;
    float* hold = hws + cur * HDIM;
    float* hnew = hws + nxt * HDIM;

    // ==== P1: GRU (+ hproj outer-product scatter) ===========================
    {
      float easum = 0.f;
      if (tid < EDIM) {
#pragma unroll
        for (int k = 0; k < 8; ++k) easum += eanx8[k * EDIM + tid];
      }
      float dp = 0.f;
      if (tid >= 512 && tid < 768) dp = denwp[tid - 512];
      smem[512 + tid] = hold[tid];
      dp = wred(dp);
      if (tid >= 512 && tid < 768 && lane == 0) smem[1632 + (wid - 8)] = dp;
      __syncthreads();
      float inv = 1.0f / (smem[1632] + smem[1633] + smem[1634] + smem[1635]);
      if (tid < EDIM) smem[tid] = easum * inv;
      __syncthreads();

      int jl = wid & 3, part = wid >> 2;
      int j = bid * 4 + jl;
      float ir = 0.f, iz = 0.f, in_ = 0.f;
#pragma unroll
      for (int k = 0; k < 2; ++k) {
        int e = part * 128 + k * 64 + lane;
        float x = smem[e];
        ir  += W_ih[(size_t)j * EDIM + e] * x;
        iz  += W_ih[(size_t)(j + HDIM) * EDIM + e] * x;
        in_ += W_ih[(size_t)(j + 2 * HDIM) * EDIM + e] * x;
      }
      float hr = 0.f, hz = 0.f, hn = 0.f;
#pragma unroll
      for (int k = 0; k < 4; ++k) {
        int e = part * 256 + k * 64 + lane;
        float x = smem[512 + e];
        hr += W_hh[(size_t)j * HDIM + e] * x;
        hz += W_hh[(size_t)(j + HDIM) * HDIM + e] * x;
        hn += W_hh[(size_t)(j + 2 * HDIM) * HDIM + e] * x;
      }
#pragma unroll
      for (int off = 32; off; off >>= 1) {
        ir += __shfl_down(ir, off);  iz += __shfl_down(iz, off);  in_ += __shfl_down(in_, off);
        hr += __shfl_down(hr, off);  hz += __shfl_down(hz, off);  hn += __shfl_down(hn, off);
      }
      if (lane == 0) {
        float* pb = smem + 1536 + (jl * 4 + part) * 6;
        pb[0] = ir; pb[1] = iz; pb[2] = in_; pb[3] = hr; pb[4] = hz; pb[5] = hn;
      }
      __syncthreads();
      if (tid < 4) {
        int jj = bid * 4 + tid;
        float sir = 0.f, siz = 0.f, sin_ = 0.f, shr = 0.f, shz = 0.f, shn = 0.f;
#pragma unroll
        for (int p = 0; p < 4; ++p) {
          float* pb = smem + 1536 + (tid * 4 + p) * 6;
          sir += pb[0]; siz += pb[1]; sin_ += pb[2];
          shr += pb[3]; shz += pb[4]; shn += pb[5];
        }
        float r = 1.f / (1.f + expf(-(sir + b_ih[jj] + shr + b_hh[jj])));
        float z = 1.f / (1.f + expf(-(siz + b_ih[jj + HDIM] + shz + b_hh[jj + HDIM])));
        float n = tanhf(sin_ + b_ih[jj + 2 * HDIM] + r * (shn + b_hh[jj + 2 * HDIM]));
        float hv = (1.f - z) * n + z * smem[512 + jj];
        hnew[jj] = hv;
        smem[1640 + tid] = hv;
      }
      __syncthreads();
      if (tid < ADIM) {
        float s = 0.f;
#pragma unroll
        for (int jl2 = 0; jl2 < 4; ++jl2)
          s += smem[1640 + jl2] * W1[(size_t)(ADIM + bid * 4 + jl2) * ADIM + tid];
        atomicAdd(&hproj8[(bid & 7) * ADIM + tid], s);
      }
    }
    rnd++; gridbar(bar, bid, rnd);

    // ==== P2: scores (reduce hproj8; esc = exp(v.tanh(P+hp)); sdenp) ========
    {
      float hp = 0.f;
      if (tid < ADIM) {
#pragma unroll
        for (int k = 0; k < 8; ++k) hp += hproj8[k * ADIM + tid];
      }
      if (tid >= 512) smem[tid] = vvec[tid - 512];
      if (tid < ADIM) smem[tid] = hp;
      if (bid < 8 && tid < EDIM) eanx8[bid * EDIM + tid] = 0.f;
      __syncthreads();
      int sl = wid & 3, part = wid >> 2;
      int s = bid * 4 + sl;
      float acc = 0.f;
#pragma unroll
      for (int k = 0; k < 2; ++k) {
        int a = part * 128 + k * 64 + lane;
        acc += smem[512 + a] * tanhf(P[(size_t)s * ADIM + a] + smem[a]);
      }
      acc = wred(acc);
      if (lane == 0) smem[1024 + wid] = acc;
      __syncthreads();
      if (tid < 4) {
        float tot = smem[1024 + tid] + smem[1028 + tid] + smem[1032 + tid] + smem[1036 + tid];
        float e = expf(tot);
        esc[bid * 4 + tid] = e;
        smem[1040 + tid] = e;
      }
      __syncthreads();
      if (tid == 0)
        sdenp[bid] = smem[1040] + smem[1041] + smem[1042] + smem[1043];
    }
    rnd++; gridbar(bar, bid, rnd);

    // ==== P3: attn + w output + zero hproj8 =================================
    {
      float sp = 0.f;
      if (tid >= 512 && tid < 768) sp = sdenp[tid - 512];
      sp = wred(sp);
      if (tid >= 512 && tid < 768 && lane == 0) smem[16 + (wid - 8)] = sp;
      int al = wid & 1, part = wid >> 1;
      int a = bid * 2 + al;
      float acc = 0.f;
#pragma unroll
      for (int k = 0; k < 2; ++k) {
        int s = part * 128 + k * 64 + lane;
        acc += embT[(size_t)a * SLEN + s] * esc[s];
      }
      acc = wred(acc);
      if (lane == 0) smem[32 + wid] = acc;
      __syncthreads();
      float sden_t = smem[16] + smem[17] + smem[18] + smem[19];
      if (tid < 2) {
        float s = 0.f;
#pragma unroll
        for (int p = 0; p < 8; ++p) s += smem[32 + tid + p * 2];
        attn[bid * 2 + tid] = s / sden_t;
      }
      if (bid < 4 && tid < 256)
        out[VOFF + (size_t)t * SLEN + bid * 256 + tid] = esc[bid * 256 + tid] / sden_t;
      if (bid < 8 && tid < ADIM) hproj8[bid * ADIM + tid] = 0.f;
    }
    rnd++; gridbar(bar, bid, rnd);

    // ==== P4: logits (guard-free quads, x in regs) + sparse feedback ========
    {
      smem[tid] = hnew[tid];
      if (tid < ADIM) smem[HDIM + tid] = attn[tid];
      __syncthreads();
      const float4* sm4 = (const float4*)smem;
      // hoist x into registers: lane's 24 dims, reused for all 13 rows
      float4 xf[6];
#pragma unroll
      for (int k = 0; k < 3; ++k) {
        xf[2 * k]     = sm4[k * 128 + lane * 2];
        xf[2 * k + 1] = sm4[k * 128 + lane * 2 + 1];
      }
      float* vout = out + (size_t)t * LANG;
      const bool fb = (t + 1 < NSTEP);
      float dsum = 0.f;
      float wmax = -3.4e38f;
      float vvs[13];
      int wv = bid * 16 + wid;
      // 12 guard-free rows (wv + r*4096 <= 4095 + 11*4096 = 49151 < LANG)
#pragma unroll
      for (int r0 = 0; r0 < 12; r0 += 4) {
        uint4 u[4][3];
#pragma unroll
        for (int q = 0; q < 4; ++q) {
          const uint4* rw = oW4 + (size_t)(wv + (r0 + q) * 4096) * 192;
          u[q][0] = rw[lane];
          u[q][1] = rw[64 + lane];
          u[q][2] = rw[128 + lane];
        }
        float acc[4] = {0.f, 0.f, 0.f, 0.f};
#pragma unroll
        for (int q = 0; q < 4; ++q) {
#pragma unroll
          for (int k = 0; k < 3; ++k) {
            uint4 uu = u[q][k];
            float4 b0 = xf[2 * k], b1 = xf[2 * k + 1];
            acc[q] += __uint_as_float(uu.x << 16) * b0.x + __uint_as_float(uu.x & 0xFFFF0000u) * b0.y;
            acc[q] += __uint_as_float(uu.y << 16) * b0.z + __uint_as_float(uu.y & 0xFFFF0000u) * b0.w;
            acc[q] += __uint_as_float(uu.z << 16) * b1.x + __uint_as_float(uu.z & 0xFFFF0000u) * b1.y;
            acc[q] += __uint_as_float(uu.w << 16) * b1.z + __uint_as_float(uu.w & 0xFFFF0000u) * b1.w;
          }
        }
#pragma unroll
        for (int off = 32; off; off >>= 1) {
          acc[0] += __shfl_down(acc[0], off);
          acc[1] += __shfl_down(acc[1], off);
          acc[2] += __shfl_down(acc[2], off);
          acc[3] += __shfl_down(acc[3], off);
        }
#pragma unroll
        for (int q = 0; q < 4; ++q) {
          int l = wv + (r0 + q) * 4096;
          float bc = __shfl(acc[q], 0);
          float vv = (bc + out_b[l]) * TEMPF;
          if (lane == 0) vout[l] = vv;
          wmax = fmaxf(wmax, vv);
          if (fb) dsum += expf(vv);
          vvs[r0 + q] = vv;
        }
      }
      // tail: rows 49152 + wv, wv < 1105
      {
        float vv = -3.4e38f;
        if (wv < LANG - 49152) {
          int l = 49152 + wv;
          const uint4* rw = oW4 + (size_t)l * 192;
          uint4 u0 = rw[lane], u1 = rw[64 + lane], u2 = rw[128 + lane];
          float acc = 0.f;
          uint4 uu = u0; float4 b0 = xf[0], b1 = xf[1];
          acc += __uint_as_float(uu.x << 16) * b0.x + __uint_as_float(uu.x & 0xFFFF0000u) * b0.y;
          acc += __uint_as_float(uu.y << 16) * b0.z + __uint_as_float(uu.y & 0xFFFF0000u) * b0.w;
          acc += __uint_as_float(uu.z << 16) * b1.x + __uint_as_float(uu.z & 0xFFFF0000u) * b1.y;
          acc += __uint_as_float(uu.w << 16) * b1.z + __uint_as_float(uu.w & 0xFFFF0000u) * b1.w;
          uu = u1; b0 = xf[2]; b1 = xf[3];
          acc += __uint_as_float(uu.x << 16) * b0.x + __uint_as_float(uu.x & 0xFFFF0000u) * b0.y;
          acc += __uint_as_float(uu.y << 16) * b0.z + __uint_as_float(uu.y & 0xFFFF0000u) * b0.w;
          acc += __uint_as_float(uu.z << 16) * b1.x + __uint_as_float(uu.z & 0xFFFF0000u) * b1.y;
          acc += __uint_as_float(uu.w << 16) * b1.z + __uint_as_float(uu.w & 0xFFFF0000u) * b1.w;
          uu = u2; b0 = xf[4]; b1 = xf[5];
          acc += __uint_as_float(uu.x << 16) * b0.x + __uint_as_float(uu.x & 0xFFFF0000u) * b0.y;
          acc += __uint_as_float(uu.y << 16) * b0.z + __uint_as_float(uu.y & 0xFFFF0000u) * b0.w;
          acc += __uint_as_float(uu.z << 16) * b1.x + __uint_as_float(uu.z & 0xFFFF0000u) * b1.y;
          acc += __uint_as_float(uu.w << 16) * b1.z + __uint_as_float(uu.w & 0xFFFF0000u) * b1.w;
          acc = wred(acc);
          float bc = __shfl(acc, 0);
          vv = (bc + out_b[l]) * TEMPF;
          if (lane == 0) vout[l] = vv;
          wmax = fmaxf(wmax, vv);
          if (fb) dsum += expf(vv);
        }
        vvs[12] = vv;
      }
      if (lane == 0) { smem[9728 + wid] = wmax; smem[9744 + wid] = dsum; }
      __syncthreads();
      if (fb) {
        if (tid == 0) {
          float tot = 0.f;
#pragma unroll
          for (int p = 0; p < 16; ++p) tot += smem[9744 + p];
          denwp[bid] = tot;
        }
        float bmax = smem[9728];
#pragma unroll
        for (int p = 1; p < 16; ++p) bmax = fmaxf(bmax, smem[9728 + p]);
        float thr = bmax - 12.0f;   // excluded mass <= LANG*e^-12 ~ 3e-4 relative
        float ae[8] = {0.f, 0.f, 0.f, 0.f, 0.f, 0.f, 0.f, 0.f};
#pragma unroll
        for (int r = 0; r < 13; ++r) {
          if (vvs[r] >= thr) {
            int l = (r < 12) ? (wv + r * 4096) : (49152 + wv);
            float ev = expf(vvs[r]);
            uint4 uu = eT4[(size_t)l * 64 + lane];
            ae[0] += ev * __uint_as_float(uu.x << 16);
            ae[1] += ev * __uint_as_float(uu.x & 0xFFFF0000u);
            ae[2] += ev * __uint_as_float(uu.y << 16);
            ae[3] += ev * __uint_as_float(uu.y & 0xFFFF0000u);
            ae[4] += ev * __uint_as_float(uu.z << 16);
            ae[5] += ev * __uint_as_float(uu.z & 0xFFFF0000u);
            ae[6] += ev * __uint_as_float(uu.w << 16);
            ae[7] += ev * __uint_as_float(uu.w & 0xFFFF0000u);
          }
        }
        float* big = smem + 1536;
#pragma unroll
        for (int i = 0; i < 8; ++i) big[wid * 512 + i * 64 + lane] = ae[i];
        __syncthreads();
#pragma unroll
        for (int st = 8; st; st >>= 1) {
          for (int i = tid; i < st * 512; i += NTHR) big[i] += big[i + st * 512];
          __syncthreads();
        }
        if (tid < 512) {
          int dim = ((tid & 63) << 3) | (tid >> 6);
          atomicAdd(&eanx8[(bid & 7) * EDIM + dim], big[tid]);
        }
      }
    }
    rnd++; gridbar(bar, bid, rnd);
  }
}

extern "C" void kernel_launch(void* const* d_in, const int* in_sizes, int n_in,
                              void* d_out, int out_size, void* d_ws, size_t ws_size,
                              hipStream_t stream) {
  const float* hidden  = (const float*)d_in[0];
  const float* emb_src = (const float*)d_in[1];
  const float* emb_T   = (const float*)d_in[2];
  const float* W_ih    = (const float*)d_in[3];
  const float* W_hh    = (const float*)d_in[4];
  const float* b_ih    = (const float*)d_in[5];
  const float* b_hh    = (const float*)d_in[6];
  const float* attn_W1 = (const float*)d_in[7];
  const float* attn_b1 = (const float*)d_in[8];
  const float* attn_v  = (const float*)d_in[9];
  const float* out_W   = (const float*)d_in[10];
  const float* out_b   = (const float*)d_in[11];
  float* out = (float*)d_out;
  char* wsb  = (char*)d_ws;

  hipMemsetAsync(wsb + OFF_BAR, 0, 2048, stream);

  void* args[] = {
    (void*)&hidden, (void*)&emb_src, (void*)&emb_T, (void*)&W_ih, (void*)&W_hh,
    (void*)&b_ih, (void*)&b_hh, (void*)&attn_W1, (void*)&attn_b1, (void*)&attn_v,
    (void*)&out_W, (void*)&out_b, (void*)&out, (void*)&wsb
  };
  hipLaunchCooperativeKernel((void*)k_decoder, dim3(NBLK), dim3(NTHR), args, 0, stream);
}